// Round 18
// baseline (117.727 us; speedup 1.0000x reference)
//
#include <hip/hip_runtime.h>
#include <hip/hip_bf16.h>

#define Hh   128
#define FH   512
#define Lz   64
#define Tt   12
#define NFf  16
#define MAXD 64    // slot-table max in-degree (Poisson(16): P(>64) ~ 1e-20)
#define L2E  1.4426950408889634f

typedef __attribute__((ext_vector_type(8))) short short8;   // 8 bf16 = 4 VGPRs
typedef __attribute__((ext_vector_type(4))) float f32x4;

// gates arrive PRE-SCALED by log2(e) (folded into Bhi/Wz/bz at prep)
__device__ __forceinline__ float sigf2(float xs) {          // sigmoid(xs/L2E)
    return __builtin_amdgcn_rcpf(1.f + exp2f(-xs));
}
__device__ __forceinline__ float ftanh2(float xs) {         // tanh(xs/L2E)
    float t = fminf(fmaxf(xs, -44.f), 44.f);
    float e = exp2f(-2.f * t);
    return (1.f - e) * __builtin_amdgcn_rcpf(1.f + e);
}
__device__ __forceinline__ unsigned short f2bf(float x) {   // round-to-nearest-even
    unsigned u = __float_as_uint(x);
    return (unsigned short)((u + 0x7FFF + ((u >> 16) & 1)) >> 16);
}
__device__ __forceinline__ float bf2f(unsigned short s) {
    return __uint_as_float(((unsigned)s) << 16);
}

// ================= fused prep =================
// block ranges: [node_mask | csr-direct | pack_whh | pack_wc | pack_wz | bz | pack_wf2]

__global__ __launch_bounds__(256) void prep_misc_k(
    const unsigned char* __restrict__ xm, const int* __restrict__ edge,
    const float* __restrict__ Whh, const float* __restrict__ Wg,
    const float* __restrict__ W3,  const float* __restrict__ bg,
    const float* __restrict__ b3,  const float* __restrict__ Wf2,
    const float* __restrict__ Wih, const float* __restrict__ bf2,
    const float* __restrict__ bih, const float* __restrict__ bhh,
    float* __restrict__ mask, int* __restrict__ cursor, int* __restrict__ colsrc,
    unsigned short* __restrict__ Bhi, unsigned short* __restrict__ Wchi,
    float* __restrict__ bc,
    unsigned short* __restrict__ Wzh, unsigned short* __restrict__ Wzl,
    unsigned short* __restrict__ Wf2h, unsigned short* __restrict__ Wf2l,
    float* __restrict__ bz,
    int Nn, int E)
{
    int tid = threadIdx.x, b = blockIdx.x;
    int nbm = (Nn + 255) >> 8, nbd = (E + 255) >> 8;
    int t1 = nbm, t2 = t1 + nbd, t3 = t2 + 256, t4 = t3 + 17, t5 = t4 + 128, t6 = t5 + 2;

    if (b < t1) {                    // ---- node_mask ----
        int n = b * 256 + tid;
        if (n >= Nn) return;
        const unsigned int* p = (const unsigned int*)(xm + (size_t)n * 192);
        unsigned int o = 0;
#pragma unroll
        for (int i = 0; i < 48; ++i) o |= p[i];
        mask[n] = o ? 1.0f : 0.0f;
    } else if (b < t2) {             // ---- direct slot-table CSR ----
        int e = (b - t1) * 256 + tid;
        if (e >= E) return;
        int s = edge[e];             s = s < 0 ? 0 : (s >= Nn ? Nn - 1 : s);
        int d = edge[(size_t)E + e]; d = d < 0 ? 0 : (d >= Nn ? Nn - 1 : d);
        int pos = atomicAdd(&cursor[d], 1);
        if (pos < MAXD) colsrc[(size_t)d * MAXD + pos] = s;
    } else if (b < t3) {             // ---- pack W_hh -> B-frag, bf16 hi, scaled by L2E ----
        int gid = (b - t2) * 256 + tid;      // < 65536
        int e  = gid & 7;
        int l  = (gid >> 3) & 63;
        int kt = (gid >> 9) & 3;
        int c  = gid >> 11;
        int k = kt * 32 + (l >> 4) * 8 + e;
        int j = c * 16 + (l & 15);
        Bhi[gid] = f2bf(Whh[j * Hh + k] * L2E);
    } else if (b < t4) {             // ---- pack Wc = Wg@W3 (+bc), UNscaled ----
        int gid = (b - t3) * 256 + tid;
        if (gid < 4096) {
            int e = gid & 7, l = (gid >> 3) & 63, kt = gid >> 9;
            int k = kt * 32 + (l >> 4) * 8 + e, f = l & 15;
            const float* a = Wg + k * Hh;
            float s = 0.f;
#pragma unroll 4
            for (int h = 0; h < Hh; ++h) s += a[h] * W3[h * NFf + f];
            Wchi[gid] = f2bf(s);
        } else if (gid < 4096 + NFf) {
            int f = gid - 4096;
            float s = b3[f];
#pragma unroll 4
            for (int h = 0; h < Hh; ++h) s += bg[h] * W3[h * NFf + f];
            bc[f] = s;
        }
    } else if (b < t5) {             // ---- pack Wz = Wf2@Wih^T in B-frag order, hi/lo, scaled ----
        int gid = (b - t4) * 256 + tid;      // < 32768
        int e = gid & 7, l = (gid >> 3) & 63;
        int ktc = gid >> 9;                  // c*2+kt, c<32
        int kt = ktc & 1, c = ktc >> 1;
        int k = kt * 32 + (l >> 4) * 8 + e;  // z-dim (0..63)
        int j = c * 16 + (l & 15);           // gate-col (0..511)
        const float* a = Wf2 + k * Hh;
        const float* bb = Wih + j * Hh;
        float s = 0.f;
#pragma unroll 4
        for (int h = 0; h < Hh; ++h) s += a[h] * bb[h];
        s *= L2E;
        unsigned short hi = f2bf(s);
        Wzh[gid] = hi;
        Wzl[gid] = f2bf(s - bf2f(hi));
    } else if (b < t6) {             // ---- bz = (bf2@Wih^T + bih + bhh) * L2E ----
        int j = (b - t5) * 256 + tid;
        if (j >= FH) return;
        const float* bb = Wih + j * Hh;
        float s = bih[j] + bhh[j];
#pragma unroll 4
        for (int k = 0; k < Hh; ++k) s += bf2[k] * bb[k];
        bz[j] = s * L2E;
    } else {                         // ---- pack W_fc2 -> B-frag, hi/lo, UNscaled ----
        int gid = (b - t6) * 256 + tid;      // < 8192
        int e = gid & 7, l = (gid >> 3) & 63;
        int ktc = gid >> 9;                  // c*2+kt, c<8
        int kt = ktc & 1, c = ktc >> 1;
        int k = kt * 32 + (l >> 4) * 8 + e;  // z-dim
        int j = c * 16 + (l & 15);           // hidden col (0..127)
        float v = Wf2[k * Hh + j];
        unsigned short hi = f2bf(v);
        Wf2h[gid] = hi;
        Wf2l[gid] = f2bf(v - bf2f(hi));
    }
}

// ================= whole-sequence LSTM (+MFMA input projections) =================
// 16 rows/block, 8 waves x 512 thr; wave w owns m-tile w; hi-only A in recurrence.
// Gates pre-scaled by log2e (exp2-direct pointwise). kt-outer MFMA order for
// explicit 4-chain ILP; s_setprio(1) around MFMA cluster (T5: role diversity
// from the rotating pw wave). h in packed-dword double-buffered LDS; one
// barrier/step; W_hh frags resident in 64 VGPRs. Rule #20 throughout.

__global__ __launch_bounds__(512) void lstm_all_k(
    const float* __restrict__ z,
    const unsigned short* __restrict__ Wzh, const unsigned short* __restrict__ Wzl,
    const unsigned short* __restrict__ Wf2h, const unsigned short* __restrict__ Wf2l,
    const float* __restrict__ bz, const float* __restrict__ bfc2,
    const unsigned short* __restrict__ Bhi,
    const unsigned short* __restrict__ Wchi,
    const float* __restrict__ mask,
    unsigned short* __restrict__ pw, int Nn)
{
    __shared__ __align__(16) unsigned int hS[2][16 * 68];   // 2 x 4352B
    int tid = threadIdx.x, l = tid & 63, wid = tid >> 6;    // wid = m-tile
    int n0 = blockIdx.x * 16;
    int i0 = l & 15, q = l >> 4;
    int j = wid * 16 + i0;                                  // hidden column
    int gI = j >> 3, oI = (j >> 1) & 3;                     // packed write group/offset

    // W_hh B-fragments resident (16 short8 = 64 VGPRs)
    short8 Bf[4][4];
#pragma unroll
    for (int g = 0; g < 4; ++g) {
        int cidx = g * 8 + wid;
#pragma unroll
        for (int kt = 0; kt < 4; ++kt)
            Bf[g][kt] = ((const short8*)Bhi)[((cidx << 2) + kt) * 64 + l];
    }

    float mk;
    { int n = n0 + i0; mk = (n < Nn) ? mask[n] : 0.f; }

    // ---- phase 0: stage z (aliased onto hS[0]) ----
    float* z_s = (float*)&hS[0][0];                         // 1024 floats
    for (int idx = tid; idx < 16 * Lz; idx += 512) {
        int r = idx >> 6, k = idx & 63;
        int n = n0 + r;
        z_s[idx] = (n < Nn) ? z[(size_t)n * Lz + k] : 0.f;
    }
    __syncthreads();

    // z A-fragments (hi/lo trunc split), kt = 0..1
    short8 Zh[2], Zl[2];
#pragma unroll
    for (int kt = 0; kt < 2; ++kt) {
        float4 v0 = *(const float4*)&z_s[i0 * 64 + kt * 32 + q * 8];
        float4 v1 = *(const float4*)&z_s[i0 * 64 + kt * 32 + q * 8 + 4];
        float vv[8] = {v0.x, v0.y, v0.z, v0.w, v1.x, v1.y, v1.z, v1.w};
        short8 h8, l8;
#pragma unroll
        for (int e = 0; e < 8; ++e) {
            unsigned u = __float_as_uint(vv[e]);
            h8[e] = (short)(u >> 16);
            l8[e] = (short)f2bf(vv[e] - __uint_as_float(u & 0xFFFF0000u));
        }
        Zh[kt] = h8; Zl[kt] = l8;
    }

    // xpr = z@Wz + bz (4 gates, pre-scaled) via MFMA
    float4 xpr[4];
    {
        f32x4 accG[4];
#pragma unroll
        for (int g = 0; g < 4; ++g) {
            f32x4 a = (f32x4){0.f, 0.f, 0.f, 0.f};
            int cidx = g * 8 + wid;
#pragma unroll
            for (int kt = 0; kt < 2; ++kt) {
                short8 wh = ((const short8*)Wzh)[((cidx << 1) + kt) * 64 + l];
                short8 wl = ((const short8*)Wzl)[((cidx << 1) + kt) * 64 + l];
                a = __builtin_amdgcn_mfma_f32_16x16x32_bf16(Zh[kt], wh, a, 0, 0, 0);
                a = __builtin_amdgcn_mfma_f32_16x16x32_bf16(Zl[kt], wh, a, 0, 0, 0);
                a = __builtin_amdgcn_mfma_f32_16x16x32_bf16(Zh[kt], wl, a, 0, 0, 0);
            }
            accG[g] = a;
        }
        float b0 = bz[j], b1 = bz[128 + j], b2 = bz[256 + j], b3v = bz[384 + j];
#pragma unroll
        for (int r = 0; r < 4; ++r)
            xpr[r] = make_float4(accG[0][r] + b0, accG[1][r] + b1,
                                 accG[2][r] + b2, accG[3][r] + b3v);
    }

    // h0 = z@Wfc2 + bfc2 via MFMA (ctile = wid), UNscaled
    {
        f32x4 a = (f32x4){0.f, 0.f, 0.f, 0.f};
#pragma unroll
        for (int kt = 0; kt < 2; ++kt) {
            short8 wh = ((const short8*)Wf2h)[((wid << 1) + kt) * 64 + l];
            short8 wl = ((const short8*)Wf2l)[((wid << 1) + kt) * 64 + l];
            a = __builtin_amdgcn_mfma_f32_16x16x32_bf16(Zh[kt], wh, a, 0, 0, 0);
            a = __builtin_amdgcn_mfma_f32_16x16x32_bf16(Zl[kt], wh, a, 0, 0, 0);
            a = __builtin_amdgcn_mfma_f32_16x16x32_bf16(Zh[kt], wl, a, 0, 0, 0);
        }
        float bf = bfc2[j];
#pragma unroll
        for (int r = 0; r < 4; ++r) {
            int i = q * 4 + r;
            unsigned short us = f2bf(a[r] + bf);
            unsigned ot = (unsigned)__shfl_xor((int)us, 1);
            if (!(i0 & 1))
                hS[1][i * 68 + (((gI + 2 * i) & 15) << 2) + oI] = (unsigned)us | (ot << 16);
        }
    }
    __syncthreads();   // h0 visible; all z_s reads complete

    // initial A-fragments from hS[1]
    short8 Ahi[4];
#pragma unroll
    for (int kt = 0; kt < 4; ++kt) {
        int p = ((kt * 4 + q) + 2 * i0) & 15;
        Ahi[kt] = *(const short8*)&hS[1][i0 * 68 + (p << 2)];
    }

    float cC[4] = {};

    for (int t = 0; t < Tt; ++t) {
        unsigned int* hh = hS[t & 1];

        // ---- gates GEMM: kt-outer (4 independent acc chains), setprio'd ----
        f32x4 acc[4];
#pragma unroll
        for (int g = 0; g < 4; ++g) acc[g] = (f32x4){0.f, 0.f, 0.f, 0.f};
        __builtin_amdgcn_s_setprio(1);
#pragma unroll
        for (int kt = 0; kt < 4; ++kt)
#pragma unroll
            for (int g = 0; g < 4; ++g)
                acc[g] = __builtin_amdgcn_mfma_f32_16x16x32_bf16(Ahi[kt], Bf[g][kt], acc[g], 0, 0, 0);
        __builtin_amdgcn_s_setprio(0);

        // ---- pointwise (exp2-direct, gates pre-scaled) ----
#pragma unroll
        for (int r = 0; r < 4; ++r) {
            int i = q * 4 + r;
            float4 xg = xpr[r];
            float gi = acc[0][r] + xg.x;
            float gf = acc[1][r] + xg.y;
            float gg = acc[2][r] + xg.z;
            float go = acc[3][r] + xg.w;
            float cn = sigf2(gf) * cC[r] + sigf2(gi) * ftanh2(gg);
            float hn = sigf2(go) * ftanh2(cn * L2E);
            cC[r] = cn;
            unsigned short us = f2bf(hn);
            unsigned ot = (unsigned)__shfl_xor((int)us, 1);
            if (!(i0 & 1))
                hh[i * 68 + (((gI + 2 * i) & 15) << 2) + oI] = (unsigned)us | (ot << 16);
        }
        __syncthreads();   // single barrier per step (double-buffered h)

        // ---- rebuild A-fragments: 4x b128 ----
#pragma unroll
        for (int kt = 0; kt < 4; ++kt) {
            int p = ((kt * 4 + q) + 2 * i0) & 15;
            Ahi[kt] = *(const short8*)&hh[i0 * 68 + (p << 2)];
        }

        // ---- pw[n][t][:] = (mask*h_t) @ Wc  (rotating wave; Wc L1-hot) ----
        if (wid == (t & 7)) {
            f32x4 p = (f32x4){0.f, 0.f, 0.f, 0.f};
            bool on = (mk != 0.f);
            short8 zz = (short8)(short)0;
#pragma unroll
            for (int kt = 0; kt < 4; ++kt) {
                short8 wh = ((const short8*)Wchi)[kt * 64 + l];
                p = __builtin_amdgcn_mfma_f32_16x16x32_bf16(on ? Ahi[kt] : zz, wh, p, 0, 0, 0);
            }
#pragma unroll
            for (int r = 0; r < 4; ++r) {
                int n = n0 + q * 4 + r;
                if (n < Nn) pw[((size_t)n * Tt + t) * NFf + i0] = f2bf(p[r]);
            }
        }
    }
}

// ================= aggregate + bias -> out =================
// lane-parallel neighbor prefetch; loop = shfl broadcast + independent gathers.

__global__ __launch_bounds__(256) void agg_out_k(
    const unsigned short* __restrict__ pw, const int* __restrict__ cursor,
    const int* __restrict__ colsrc, const float* __restrict__ bc,
    float* __restrict__ out, int Nn)
{
    int lane = threadIdx.x & 63;
    int n = blockIdx.x * 4 + (threadIdx.x >> 6);
    if (n >= Nn) return;
    int deg = cursor[n]; if (deg > MAXD - 1) deg = MAXD - 1;   // keep slot for self
    float dv = rsqrtf((float)(deg + 1));

    int colv = n;
    float wv = 0.f;
    if (lane < deg) {
        colv = colsrc[(size_t)n * MAXD + lane];
        int dc = cursor[colv]; if (dc > MAXD - 1) dc = MAXD - 1;
        wv = rsqrtf((float)(dc + 1));
    } else if (lane == deg) {
        colv = n; wv = dv;                                     // self loop
    }

    const unsigned int* pw32 = (const unsigned int*)pw;
    float a0 = 0.f, a1 = 0.f, a2 = 0.f, a3 = 0.f;
    int cnt = deg + 1;
    for (int e = 0; e < cnt; ++e) {
        int s = __shfl(colv, e, 64);
        float w = dv * __shfl(wv, e, 64);
        unsigned v0 = pw32[(size_t)s * 96 + lane];
        unsigned v1 = (lane < 32) ? pw32[(size_t)s * 96 + 64 + lane] : 0u;
        a0 += __uint_as_float(v0 << 16) * w;
        a1 += __uint_as_float(v0 & 0xFFFF0000u) * w;
        a2 += __uint_as_float(v1 << 16) * w;
        a3 += __uint_as_float(v1 & 0xFFFF0000u) * w;
    }
    int f0 = (2 * lane) & 15;
    float bc0 = bc[f0], bc1 = bc[f0 + 1];
    float* on = out + (size_t)n * 192;
    *(float2*)&on[2 * lane] = make_float2(a0 + bc0, a1 + bc1);
    if (lane < 32)
        *(float2*)&on[128 + 2 * lane] = make_float2(a2 + bc0, a3 + bc1);
}

// ================= launcher =================

extern "C" void kernel_launch(void* const* d_in, const int* in_sizes, int n_in,
                              void* d_out, int out_size, void* d_ws, size_t ws_size,
                              hipStream_t stream)
{
    const float* z     = (const float*)d_in[0];
    const int*   edge  = (const int*)d_in[1];
    const unsigned char* xmask = (const unsigned char*)d_in[2];
    const float* W_fc2 = (const float*)d_in[3];
    const float* b_fc2 = (const float*)d_in[4];
    const float* W_ih  = (const float*)d_in[5];
    const float* W_hh  = (const float*)d_in[6];
    const float* b_ih  = (const float*)d_in[7];
    const float* b_hh  = (const float*)d_in[8];
    const float* W_gcn = (const float*)d_in[9];
    const float* b_gcn = (const float*)d_in[10];
    const float* W_fc3 = (const float*)d_in[11];
    const float* b_fc3 = (const float*)d_in[12];
    float* out = (float*)d_out;

    const int N = in_sizes[0] / Lz;   // 10000
    const int E = in_sizes[1] / 2;    // 160000

    char* w = (char*)d_ws;
    auto alloc = [&](size_t bytes) { char* p = w; w += (bytes + 255) & ~(size_t)255; return p; };
    unsigned short* pw = (unsigned short*)alloc((size_t)N * Tt * NFf * 2);
    float* mask   = (float*)alloc((size_t)N * 4);
    int*   cursor = (int*)alloc((size_t)N * 4);
    int*   colsrc = (int*)alloc((size_t)N * MAXD * 4);
    unsigned short* Bhi  = (unsigned short*)alloc((size_t)FH * Hh * 2);
    unsigned short* Wchi = (unsigned short*)alloc(4096 * 2);
    unsigned short* Wzh  = (unsigned short*)alloc(32768 * 2);
    unsigned short* Wzl  = (unsigned short*)alloc(32768 * 2);
    unsigned short* Wf2h = (unsigned short*)alloc(8192 * 2);
    unsigned short* Wf2l = (unsigned short*)alloc(8192 * 2);
    float* bz     = (float*)alloc(FH * 4);
    float* bc     = (float*)alloc(NFf * 4);

    hipMemsetAsync(cursor, 0, (size_t)N * 4, stream);

    const int nbm = (N + 255) / 256;
    const int nbd = (E + 255) / 256;
    const int nb16 = (N + 15) / 16;
    const int prep_blocks = nbm + nbd + 256 + 17 + 128 + 2 + 32;

    prep_misc_k<<<prep_blocks, 256, 0, stream>>>(
        xmask, edge, W_hh, W_gcn, W_fc3, b_gcn, b_fc3, W_fc2, W_ih, b_fc2, b_ih, b_hh,
        mask, cursor, colsrc, Bhi, Wchi, bc, Wzh, Wzl, Wf2h, Wf2l, bz, N, E);
    lstm_all_k<<<nb16, 512, 0, stream>>>(z, Wzh, Wzl, Wf2h, Wf2l, bz, b_fc2,
                                         Bhi, Wchi, mask, pw, N);
    agg_out_k<<<(N + 3) / 4, 256, 0, stream>>>(pw, cursor, colsrc, bc, out, N);
}

// Round 19
// 107.685 us; speedup vs baseline: 1.0933x; 1.0933x over previous
//
#include <hip/hip_runtime.h>
#include <hip/hip_bf16.h>

#define Hh   128
#define FH   512
#define Lz   64
#define Tt   12
#define NFf  16
#define MAXD 64    // slot-table max in-degree (Poisson(16): P(>64) ~ 1e-20)

typedef __attribute__((ext_vector_type(8))) short short8;   // 8 bf16 = 4 VGPRs
typedef __attribute__((ext_vector_type(4))) float f32x4;

__device__ __forceinline__ float sigf(float x) {
    return __builtin_amdgcn_rcpf(1.f + __expf(-x));
}
__device__ __forceinline__ float ftanh(float x) {
    float xx = fminf(fmaxf(x, -15.f), 15.f);
    float e = __expf(-2.f * xx);
    return (1.f - e) * __builtin_amdgcn_rcpf(1.f + e);
}
__device__ __forceinline__ unsigned short f2bf(float x) {   // round-to-nearest-even
    unsigned u = __float_as_uint(x);
    return (unsigned short)((u + 0x7FFF + ((u >> 16) & 1)) >> 16);
}
__device__ __forceinline__ float bf2f(unsigned short s) {
    return __uint_as_float(((unsigned)s) << 16);
}

// ================= fused prep =================
// block ranges: [node_mask | csr-direct | pack_whh | pack_wc | pack_wz | bz | pack_wf2]

__global__ __launch_bounds__(256) void prep_misc_k(
    const unsigned char* __restrict__ xm, const int* __restrict__ edge,
    const float* __restrict__ Whh, const float* __restrict__ Wg,
    const float* __restrict__ W3,  const float* __restrict__ bg,
    const float* __restrict__ b3,  const float* __restrict__ Wf2,
    const float* __restrict__ Wih, const float* __restrict__ bf2,
    const float* __restrict__ bih, const float* __restrict__ bhh,
    float* __restrict__ mask, int* __restrict__ cursor, int* __restrict__ colsrc,
    unsigned short* __restrict__ Bhi, unsigned short* __restrict__ Wchi,
    float* __restrict__ bc,
    unsigned short* __restrict__ Wzh, unsigned short* __restrict__ Wzl,
    unsigned short* __restrict__ Wf2h, unsigned short* __restrict__ Wf2l,
    float* __restrict__ bz,
    int Nn, int E)
{
    int tid = threadIdx.x, b = blockIdx.x;
    int nbm = (Nn + 255) >> 8, nbd = (E + 255) >> 8;
    int t1 = nbm, t2 = t1 + nbd, t3 = t2 + 256, t4 = t3 + 17, t5 = t4 + 128, t6 = t5 + 2;

    if (b < t1) {                    // ---- node_mask ----
        int n = b * 256 + tid;
        if (n >= Nn) return;
        const unsigned int* p = (const unsigned int*)(xm + (size_t)n * 192);
        unsigned int o = 0;
#pragma unroll
        for (int i = 0; i < 48; ++i) o |= p[i];
        mask[n] = o ? 1.0f : 0.0f;
    } else if (b < t2) {             // ---- direct slot-table CSR ----
        int e = (b - t1) * 256 + tid;
        if (e >= E) return;
        int s = edge[e];             s = s < 0 ? 0 : (s >= Nn ? Nn - 1 : s);
        int d = edge[(size_t)E + e]; d = d < 0 ? 0 : (d >= Nn ? Nn - 1 : d);
        int pos = atomicAdd(&cursor[d], 1);
        if (pos < MAXD) colsrc[(size_t)d * MAXD + pos] = s;
    } else if (b < t3) {             // ---- pack W_hh -> B-frag, bf16 hi ----
        int gid = (b - t2) * 256 + tid;      // < 65536
        int e  = gid & 7;
        int l  = (gid >> 3) & 63;
        int kt = (gid >> 9) & 3;
        int c  = gid >> 11;
        int k = kt * 32 + (l >> 4) * 8 + e;
        int j = c * 16 + (l & 15);
        Bhi[gid] = f2bf(Whh[j * Hh + k]);
    } else if (b < t4) {             // ---- pack Wc = Wg@W3 (+bc) ----
        int gid = (b - t3) * 256 + tid;
        if (gid < 4096) {
            int e = gid & 7, l = (gid >> 3) & 63, kt = gid >> 9;
            int k = kt * 32 + (l >> 4) * 8 + e, f = l & 15;
            const float* a = Wg + k * Hh;
            float s = 0.f;
#pragma unroll 4
            for (int h = 0; h < Hh; ++h) s += a[h] * W3[h * NFf + f];
            Wchi[gid] = f2bf(s);
        } else if (gid < 4096 + NFf) {
            int f = gid - 4096;
            float s = b3[f];
#pragma unroll 4
            for (int h = 0; h < Hh; ++h) s += bg[h] * W3[h * NFf + f];
            bc[f] = s;
        }
    } else if (b < t5) {             // ---- pack Wz = Wf2@Wih^T directly in B-frag order, hi/lo ----
        int gid = (b - t4) * 256 + tid;      // < 32768
        int e = gid & 7, l = (gid >> 3) & 63;
        int ktc = gid >> 9;                  // c*2+kt, c<32
        int kt = ktc & 1, c = ktc >> 1;
        int k = kt * 32 + (l >> 4) * 8 + e;  // z-dim (0..63)
        int j = c * 16 + (l & 15);           // gate-col (0..511)
        const float* a = Wf2 + k * Hh;
        const float* bb = Wih + j * Hh;
        float s = 0.f;
#pragma unroll 4
        for (int h = 0; h < Hh; ++h) s += a[h] * bb[h];
        unsigned short hi = f2bf(s);
        Wzh[gid] = hi;
        Wzl[gid] = f2bf(s - bf2f(hi));
    } else if (b < t6) {             // ---- bz = bf2@Wih^T + bih + bhh ----
        int j = (b - t5) * 256 + tid;
        if (j >= FH) return;
        const float* bb = Wih + j * Hh;
        float s = bih[j] + bhh[j];
#pragma unroll 4
        for (int k = 0; k < Hh; ++k) s += bf2[k] * bb[k];
        bz[j] = s;
    } else {                         // ---- pack W_fc2 -> B-frag, hi/lo ----
        int gid = (b - t6) * 256 + tid;      // < 8192
        int e = gid & 7, l = (gid >> 3) & 63;
        int ktc = gid >> 9;                  // c*2+kt, c<8
        int kt = ktc & 1, c = ktc >> 1;
        int k = kt * 32 + (l >> 4) * 8 + e;  // z-dim
        int j = c * 16 + (l & 15);           // hidden col (0..127)
        float v = Wf2[k * Hh + j];
        unsigned short hi = f2bf(v);
        Wf2h[gid] = hi;
        Wf2l[gid] = f2bf(v - bf2f(hi));
    }
}

// ================= whole-sequence LSTM (+MFMA input projections) =================
// 16 rows/block, 8 waves x 512 thr; wave w owns m-tile w; hi-only A in recurrence.
// Phase-0: z staged (4KB, aliased on h buffer 0) -> z A-frags (hi/lo trunc split)
// -> xpr & h0 via 30 MFMA. h in packed-dword double-buffered LDS; one
// barrier/step; W_hh frags resident in 64 VGPRs. No occupancy floor
// (round-15 lesson); no setprio/exp2/kt-outer (round-18 regression, reverted).
// Rule #20 throughout.

__global__ __launch_bounds__(512) void lstm_all_k(
    const float* __restrict__ z,
    const unsigned short* __restrict__ Wzh, const unsigned short* __restrict__ Wzl,
    const unsigned short* __restrict__ Wf2h, const unsigned short* __restrict__ Wf2l,
    const float* __restrict__ bz, const float* __restrict__ bfc2,
    const unsigned short* __restrict__ Bhi,
    const unsigned short* __restrict__ Wchi,
    const float* __restrict__ mask,
    unsigned short* __restrict__ pw, int Nn)
{
    __shared__ __align__(16) unsigned int hS[2][16 * 68];   // 2 x 4352B
    int tid = threadIdx.x, l = tid & 63, wid = tid >> 6;    // wid = m-tile
    int n0 = blockIdx.x * 16;
    int i0 = l & 15, q = l >> 4;
    int j = wid * 16 + i0;                                  // hidden column
    int gI = j >> 3, oI = (j >> 1) & 3;                     // packed write group/offset

    // W_hh B-fragments resident (16 short8 = 64 VGPRs)
    short8 Bf[4][4];
#pragma unroll
    for (int g = 0; g < 4; ++g) {
        int cidx = g * 8 + wid;
#pragma unroll
        for (int kt = 0; kt < 4; ++kt)
            Bf[g][kt] = ((const short8*)Bhi)[((cidx << 2) + kt) * 64 + l];
    }

    float mk;
    { int n = n0 + i0; mk = (n < Nn) ? mask[n] : 0.f; }

    // ---- phase 0: stage z (aliased onto hS[0]) ----
    float* z_s = (float*)&hS[0][0];                         // 1024 floats
    for (int idx = tid; idx < 16 * Lz; idx += 512) {
        int r = idx >> 6, k = idx & 63;
        int n = n0 + r;
        z_s[idx] = (n < Nn) ? z[(size_t)n * Lz + k] : 0.f;
    }
    __syncthreads();

    // z A-fragments (hi/lo trunc split), kt = 0..1
    short8 Zh[2], Zl[2];
#pragma unroll
    for (int kt = 0; kt < 2; ++kt) {
        float4 v0 = *(const float4*)&z_s[i0 * 64 + kt * 32 + q * 8];
        float4 v1 = *(const float4*)&z_s[i0 * 64 + kt * 32 + q * 8 + 4];
        float vv[8] = {v0.x, v0.y, v0.z, v0.w, v1.x, v1.y, v1.z, v1.w};
        short8 h8, l8;
#pragma unroll
        for (int e = 0; e < 8; ++e) {
            unsigned u = __float_as_uint(vv[e]);
            h8[e] = (short)(u >> 16);
            l8[e] = (short)f2bf(vv[e] - __uint_as_float(u & 0xFFFF0000u));
        }
        Zh[kt] = h8; Zl[kt] = l8;
    }

    // xpr = z@Wz + bz (4 gates) via MFMA
    float4 xpr[4];
    {
        f32x4 accG[4];
#pragma unroll
        for (int g = 0; g < 4; ++g) {
            f32x4 a = (f32x4){0.f, 0.f, 0.f, 0.f};
            int cidx = g * 8 + wid;
#pragma unroll
            for (int kt = 0; kt < 2; ++kt) {
                short8 wh = ((const short8*)Wzh)[((cidx << 1) + kt) * 64 + l];
                short8 wl = ((const short8*)Wzl)[((cidx << 1) + kt) * 64 + l];
                a = __builtin_amdgcn_mfma_f32_16x16x32_bf16(Zh[kt], wh, a, 0, 0, 0);
                a = __builtin_amdgcn_mfma_f32_16x16x32_bf16(Zl[kt], wh, a, 0, 0, 0);
                a = __builtin_amdgcn_mfma_f32_16x16x32_bf16(Zh[kt], wl, a, 0, 0, 0);
            }
            accG[g] = a;
        }
        float b0 = bz[j], b1 = bz[128 + j], b2 = bz[256 + j], b3v = bz[384 + j];
#pragma unroll
        for (int r = 0; r < 4; ++r)
            xpr[r] = make_float4(accG[0][r] + b0, accG[1][r] + b1,
                                 accG[2][r] + b2, accG[3][r] + b3v);
    }

    // h0 = z@Wfc2 + bfc2 via MFMA (ctile = wid)
    {
        f32x4 a = (f32x4){0.f, 0.f, 0.f, 0.f};
#pragma unroll
        for (int kt = 0; kt < 2; ++kt) {
            short8 wh = ((const short8*)Wf2h)[((wid << 1) + kt) * 64 + l];
            short8 wl = ((const short8*)Wf2l)[((wid << 1) + kt) * 64 + l];
            a = __builtin_amdgcn_mfma_f32_16x16x32_bf16(Zh[kt], wh, a, 0, 0, 0);
            a = __builtin_amdgcn_mfma_f32_16x16x32_bf16(Zl[kt], wh, a, 0, 0, 0);
            a = __builtin_amdgcn_mfma_f32_16x16x32_bf16(Zh[kt], wl, a, 0, 0, 0);
        }
        float bf = bfc2[j];
#pragma unroll
        for (int r = 0; r < 4; ++r) {
            int i = q * 4 + r;
            unsigned short us = f2bf(a[r] + bf);
            unsigned ot = (unsigned)__shfl_xor((int)us, 1);
            if (!(i0 & 1))
                hS[1][i * 68 + (((gI + 2 * i) & 15) << 2) + oI] = (unsigned)us | (ot << 16);
        }
    }
    __syncthreads();   // h0 visible; all z_s reads complete

    // initial A-fragments from hS[1]
    short8 Ahi[4];
#pragma unroll
    for (int kt = 0; kt < 4; ++kt) {
        int p = ((kt * 4 + q) + 2 * i0) & 15;
        Ahi[kt] = *(const short8*)&hS[1][i0 * 68 + (p << 2)];
    }

    float cC[4] = {};

    for (int t = 0; t < Tt; ++t) {
        unsigned int* hh = hS[t & 1];

        // ---- gates GEMM (16 MFMA) + pointwise (4 cells) ----
        f32x4 acc[4];
#pragma unroll
        for (int g = 0; g < 4; ++g) acc[g] = (f32x4){0.f, 0.f, 0.f, 0.f};
#pragma unroll
        for (int g = 0; g < 4; ++g)
#pragma unroll
            for (int kt = 0; kt < 4; ++kt)
                acc[g] = __builtin_amdgcn_mfma_f32_16x16x32_bf16(Ahi[kt], Bf[g][kt], acc[g], 0, 0, 0);

#pragma unroll
        for (int r = 0; r < 4; ++r) {
            int i = q * 4 + r;
            float4 xg = xpr[r];
            float gi = acc[0][r] + xg.x;
            float gf = acc[1][r] + xg.y;
            float gg = acc[2][r] + xg.z;
            float go = acc[3][r] + xg.w;
            float cn = sigf(gf) * cC[r] + sigf(gi) * ftanh(gg);
            float hn = sigf(go) * ftanh(cn);
            cC[r] = cn;
            unsigned short us = f2bf(hn);
            unsigned ot = (unsigned)__shfl_xor((int)us, 1);
            if (!(i0 & 1))
                hh[i * 68 + (((gI + 2 * i) & 15) << 2) + oI] = (unsigned)us | (ot << 16);
        }
        __syncthreads();   // single barrier per step (double-buffered h)

        // ---- rebuild A-fragments: 4x b128 ----
#pragma unroll
        for (int kt = 0; kt < 4; ++kt) {
            int p = ((kt * 4 + q) + 2 * i0) & 15;
            Ahi[kt] = *(const short8*)&hh[i0 * 68 + (p << 2)];
        }

        // ---- pw[n][t][:] = (mask*h_t) @ Wc  (rotating wave; Wc L1-hot) ----
        if (wid == (t & 7)) {
            f32x4 p = (f32x4){0.f, 0.f, 0.f, 0.f};
            bool on = (mk != 0.f);
            short8 zz = (short8)(short)0;
#pragma unroll
            for (int kt = 0; kt < 4; ++kt) {
                short8 wh = ((const short8*)Wchi)[kt * 64 + l];
                p = __builtin_amdgcn_mfma_f32_16x16x32_bf16(on ? Ahi[kt] : zz, wh, p, 0, 0, 0);
            }
#pragma unroll
            for (int r = 0; r < 4; ++r) {
                int n = n0 + q * 4 + r;
                if (n < Nn) pw[((size_t)n * Tt + t) * NFf + i0] = f2bf(p[r]);
            }
        }
    }
}

// ================= aggregate + bias -> out =================
// lane-parallel neighbor prefetch; loop = shfl broadcast + independent gathers.

__global__ __launch_bounds__(256) void agg_out_k(
    const unsigned short* __restrict__ pw, const int* __restrict__ cursor,
    const int* __restrict__ colsrc, const float* __restrict__ bc,
    float* __restrict__ out, int Nn)
{
    int lane = threadIdx.x & 63;
    int n = blockIdx.x * 4 + (threadIdx.x >> 6);
    if (n >= Nn) return;
    int deg = cursor[n]; if (deg > MAXD - 1) deg = MAXD - 1;   // keep slot for self
    float dv = rsqrtf((float)(deg + 1));

    int colv = n;
    float wv = 0.f;
    if (lane < deg) {
        colv = colsrc[(size_t)n * MAXD + lane];
        int dc = cursor[colv]; if (dc > MAXD - 1) dc = MAXD - 1;
        wv = rsqrtf((float)(dc + 1));
    } else if (lane == deg) {
        colv = n; wv = dv;                                     // self loop
    }

    const unsigned int* pw32 = (const unsigned int*)pw;
    float a0 = 0.f, a1 = 0.f, a2 = 0.f, a3 = 0.f;
    int cnt = deg + 1;
    for (int e = 0; e < cnt; ++e) {
        int s = __shfl(colv, e, 64);
        float w = dv * __shfl(wv, e, 64);
        unsigned v0 = pw32[(size_t)s * 96 + lane];
        unsigned v1 = (lane < 32) ? pw32[(size_t)s * 96 + 64 + lane] : 0u;
        a0 += __uint_as_float(v0 << 16) * w;
        a1 += __uint_as_float(v0 & 0xFFFF0000u) * w;
        a2 += __uint_as_float(v1 << 16) * w;
        a3 += __uint_as_float(v1 & 0xFFFF0000u) * w;
    }
    int f0 = (2 * lane) & 15;
    float bc0 = bc[f0], bc1 = bc[f0 + 1];
    float* on = out + (size_t)n * 192;
    *(float2*)&on[2 * lane] = make_float2(a0 + bc0, a1 + bc1);
    if (lane < 32)
        *(float2*)&on[128 + 2 * lane] = make_float2(a2 + bc0, a3 + bc1);
}

// ================= launcher =================

extern "C" void kernel_launch(void* const* d_in, const int* in_sizes, int n_in,
                              void* d_out, int out_size, void* d_ws, size_t ws_size,
                              hipStream_t stream)
{
    const float* z     = (const float*)d_in[0];
    const int*   edge  = (const int*)d_in[1];
    const unsigned char* xmask = (const unsigned char*)d_in[2];
    const float* W_fc2 = (const float*)d_in[3];
    const float* b_fc2 = (const float*)d_in[4];
    const float* W_ih  = (const float*)d_in[5];
    const float* W_hh  = (const float*)d_in[6];
    const float* b_ih  = (const float*)d_in[7];
    const float* b_hh  = (const float*)d_in[8];
    const float* W_gcn = (const float*)d_in[9];
    const float* b_gcn = (const float*)d_in[10];
    const float* W_fc3 = (const float*)d_in[11];
    const float* b_fc3 = (const float*)d_in[12];
    float* out = (float*)d_out;

    const int N = in_sizes[0] / Lz;   // 10000
    const int E = in_sizes[1] / 2;    // 160000

    char* w = (char*)d_ws;
    auto alloc = [&](size_t bytes) { char* p = w; w += (bytes + 255) & ~(size_t)255; return p; };
    unsigned short* pw = (unsigned short*)alloc((size_t)N * Tt * NFf * 2);
    float* mask   = (float*)alloc((size_t)N * 4);
    int*   cursor = (int*)alloc((size_t)N * 4);
    int*   colsrc = (int*)alloc((size_t)N * MAXD * 4);
    unsigned short* Bhi  = (unsigned short*)alloc((size_t)FH * Hh * 2);
    unsigned short* Wchi = (unsigned short*)alloc(4096 * 2);
    unsigned short* Wzh  = (unsigned short*)alloc(32768 * 2);
    unsigned short* Wzl  = (unsigned short*)alloc(32768 * 2);
    unsigned short* Wf2h = (unsigned short*)alloc(8192 * 2);
    unsigned short* Wf2l = (unsigned short*)alloc(8192 * 2);
    float* bz     = (float*)alloc(FH * 4);
    float* bc     = (float*)alloc(NFf * 4);

    hipMemsetAsync(cursor, 0, (size_t)N * 4, stream);

    const int nbm = (N + 255) / 256;
    const int nbd = (E + 255) / 256;
    const int nb16 = (N + 15) / 16;
    const int prep_blocks = nbm + nbd + 256 + 17 + 128 + 2 + 32;

    prep_misc_k<<<prep_blocks, 256, 0, stream>>>(
        xmask, edge, W_hh, W_gcn, W_fc3, b_gcn, b_fc3, W_fc2, W_ih, b_fc2, b_ih, b_hh,
        mask, cursor, colsrc, Bhi, Wchi, bc, Wzh, Wzl, Wf2h, Wf2l, bz, N, E);
    lstm_all_k<<<nb16, 512, 0, stream>>>(z, Wzh, Wzl, Wf2h, Wf2l, bz, b_fc2,
                                         Bhi, Wchi, mask, pw, N);
    agg_out_k<<<(N + 3) / 4, 256, 0, stream>>>(pw, cursor, colsrc, bc, out, N);
}

// Round 20
// 91.081 us; speedup vs baseline: 1.2925x; 1.1823x over previous
//
#include <hip/hip_runtime.h>
#include <hip/hip_bf16.h>

#define Hh   128
#define FH   512
#define Lz   64
#define Tt   12
#define NFf  16
#define MAXD 64    // slot-table max in-degree (Poisson(16): P(>64) ~ 1e-20)
#define HRS  144   // h LDS row stride in ushorts (288B = slot shift 2 per row)

typedef __attribute__((ext_vector_type(8))) short short8;   // 8 bf16 = 4 VGPRs
typedef __attribute__((ext_vector_type(4))) float f32x4;

__device__ __forceinline__ float sigf(float x) {
    return __builtin_amdgcn_rcpf(1.f + __expf(-x));
}
__device__ __forceinline__ float ftanh(float x) {
    float xx = fminf(fmaxf(x, -15.f), 15.f);
    float e = __expf(-2.f * xx);
    return (1.f - e) * __builtin_amdgcn_rcpf(1.f + e);
}
__device__ __forceinline__ unsigned short f2bf(float x) {   // round-to-nearest-even
    unsigned u = __float_as_uint(x);
    return (unsigned short)((u + 0x7FFF + ((u >> 16) & 1)) >> 16);
}
__device__ __forceinline__ float bf2f(unsigned short s) {
    return __uint_as_float(((unsigned)s) << 16);
}

// ================= fused prep =================
// block ranges: [node_mask | csr-direct | pack_whh | pack_wc | pack_wz | bz | pack_wf2]

__global__ __launch_bounds__(256) void prep_misc_k(
    const unsigned char* __restrict__ xm, const int* __restrict__ edge,
    const float* __restrict__ Whh, const float* __restrict__ Wg,
    const float* __restrict__ W3,  const float* __restrict__ bg,
    const float* __restrict__ b3,  const float* __restrict__ Wf2,
    const float* __restrict__ Wih, const float* __restrict__ bf2,
    const float* __restrict__ bih, const float* __restrict__ bhh,
    float* __restrict__ mask, int* __restrict__ cursor, int* __restrict__ colsrc,
    unsigned short* __restrict__ Bhi, unsigned short* __restrict__ Wchi,
    float* __restrict__ bc,
    unsigned short* __restrict__ Wzh, unsigned short* __restrict__ Wzl,
    unsigned short* __restrict__ Wf2h, unsigned short* __restrict__ Wf2l,
    float* __restrict__ bz,
    int Nn, int E)
{
    int tid = threadIdx.x, b = blockIdx.x;
    int nbm = (Nn + 255) >> 8, nbd = (E + 255) >> 8;
    int t1 = nbm, t2 = t1 + nbd, t3 = t2 + 256, t4 = t3 + 17, t5 = t4 + 128, t6 = t5 + 2;

    if (b < t1) {                    // ---- node_mask ----
        int n = b * 256 + tid;
        if (n >= Nn) return;
        const unsigned int* p = (const unsigned int*)(xm + (size_t)n * 192);
        unsigned int o = 0;
#pragma unroll
        for (int i = 0; i < 48; ++i) o |= p[i];
        mask[n] = o ? 1.0f : 0.0f;
    } else if (b < t2) {             // ---- direct slot-table CSR ----
        int e = (b - t1) * 256 + tid;
        if (e >= E) return;
        int s = edge[e];             s = s < 0 ? 0 : (s >= Nn ? Nn - 1 : s);
        int d = edge[(size_t)E + e]; d = d < 0 ? 0 : (d >= Nn ? Nn - 1 : d);
        int pos = atomicAdd(&cursor[d], 1);
        if (pos < MAXD) colsrc[(size_t)d * MAXD + pos] = s;
    } else if (b < t3) {             // ---- pack W_hh -> B-frag, bf16 hi ----
        int gid = (b - t2) * 256 + tid;      // < 65536
        int e  = gid & 7;
        int l  = (gid >> 3) & 63;
        int kt = (gid >> 9) & 3;
        int c  = gid >> 11;
        int k = kt * 32 + (l >> 4) * 8 + e;
        int j = c * 16 + (l & 15);
        Bhi[gid] = f2bf(Whh[j * Hh + k]);
    } else if (b < t4) {             // ---- pack Wc = Wg@W3 (+bc) ----
        int gid = (b - t3) * 256 + tid;
        if (gid < 4096) {
            int e = gid & 7, l = (gid >> 3) & 63, kt = gid >> 9;
            int k = kt * 32 + (l >> 4) * 8 + e, f = l & 15;
            const float* a = Wg + k * Hh;
            float s = 0.f;
#pragma unroll 4
            for (int h = 0; h < Hh; ++h) s += a[h] * W3[h * NFf + f];
            Wchi[gid] = f2bf(s);
        } else if (gid < 4096 + NFf) {
            int f = gid - 4096;
            float s = b3[f];
#pragma unroll 4
            for (int h = 0; h < Hh; ++h) s += bg[h] * W3[h * NFf + f];
            bc[f] = s;
        }
    } else if (b < t5) {             // ---- pack Wz = Wf2@Wih^T directly in B-frag order, hi/lo ----
        int gid = (b - t4) * 256 + tid;      // < 32768
        int e = gid & 7, l = (gid >> 3) & 63;
        int ktc = gid >> 9;                  // c*2+kt, c<32
        int kt = ktc & 1, c = ktc >> 1;
        int k = kt * 32 + (l >> 4) * 8 + e;  // z-dim (0..63)
        int j = c * 16 + (l & 15);           // gate-col (0..511)
        const float* a = Wf2 + k * Hh;
        const float* bb = Wih + j * Hh;
        float s = 0.f;
#pragma unroll 4
        for (int h = 0; h < Hh; ++h) s += a[h] * bb[h];
        unsigned short hi = f2bf(s);
        Wzh[gid] = hi;
        Wzl[gid] = f2bf(s - bf2f(hi));
    } else if (b < t6) {             // ---- bz = bf2@Wih^T + bih + bhh ----
        int j = (b - t5) * 256 + tid;
        if (j >= FH) return;
        const float* bb = Wih + j * Hh;
        float s = bih[j] + bhh[j];
#pragma unroll 4
        for (int k = 0; k < Hh; ++k) s += bf2[k] * bb[k];
        bz[j] = s;
    } else {                         // ---- pack W_fc2 -> B-frag, hi/lo ----
        int gid = (b - t6) * 256 + tid;      // < 8192
        int e = gid & 7, l = (gid >> 3) & 63;
        int ktc = gid >> 9;                  // c*2+kt, c<8
        int kt = ktc & 1, c = ktc >> 1;
        int k = kt * 32 + (l >> 4) * 8 + e;  // z-dim
        int j = c * 16 + (l & 15);           // hidden col (0..127)
        float v = Wf2[k * Hh + j];
        unsigned short hi = f2bf(v);
        Wf2h[gid] = hi;
        Wf2l[gid] = f2bf(v - bf2f(hi));
    }
}

// ================= whole-sequence LSTM (+MFMA input projections) =================
// 16 rows/block, 8 waves x 512 thr; wave w owns m-tile w; hi-only A in recurrence.
// ROUND-20: h exchange via DIRECT ds_write_b16 (no shfl_xor/pack, no divergent
// half-wave write). Layout: row stride 144 u16 (288B -> slot shift 2/row),
// group swizzle G=(g+2*(row>>2))&15: write slot=(2r+g+2q)%8 -> q-groups on
// disjoint slot pairs = exact 2 lanes/bank (free); read spread unchanged.
// No occupancy floor (r15 lesson); no setprio/exp2/kt-outer (r18 regression).

__global__ __launch_bounds__(512) void lstm_all_k(
    const float* __restrict__ z,
    const unsigned short* __restrict__ Wzh, const unsigned short* __restrict__ Wzl,
    const unsigned short* __restrict__ Wf2h, const unsigned short* __restrict__ Wf2l,
    const float* __restrict__ bz, const float* __restrict__ bfc2,
    const unsigned short* __restrict__ Bhi,
    const unsigned short* __restrict__ Wchi,
    const float* __restrict__ mask,
    unsigned short* __restrict__ pw, int Nn)
{
    __shared__ __align__(16) unsigned short hS16[2][16 * HRS];   // 2 x 4608B
    int tid = threadIdx.x, l = tid & 63, wid = tid >> 6;    // wid = m-tile
    int n0 = blockIdx.x * 16;
    int i0 = l & 15, q = l >> 4;
    int j = wid * 16 + i0;                                  // hidden column

    // write address pieces: row = q*4+r, g = 2*wid + (i0>>3), G = (g+2q)&15
    int wG = ((2 * wid + (i0 >> 3) + 2 * q) & 15) * 8 + (i0 & 7);
    int wbase = q * 4 * HRS + wG;                           // + r*HRS per cell

    // W_hh B-fragments resident (16 short8 = 64 VGPRs)
    short8 Bf[4][4];
#pragma unroll
    for (int g = 0; g < 4; ++g) {
        int cidx = g * 8 + wid;
#pragma unroll
        for (int kt = 0; kt < 4; ++kt)
            Bf[g][kt] = ((const short8*)Bhi)[((cidx << 2) + kt) * 64 + l];
    }

    float mk;
    { int n = n0 + i0; mk = (n < Nn) ? mask[n] : 0.f; }

    // ---- phase 0: stage z (aliased onto hS16[0], 4096B <= 4608B) ----
    float* z_s = (float*)&hS16[0][0];
    for (int idx = tid; idx < 16 * Lz; idx += 512) {
        int r = idx >> 6, k = idx & 63;
        int n = n0 + r;
        z_s[idx] = (n < Nn) ? z[(size_t)n * Lz + k] : 0.f;
    }
    __syncthreads();

    // z A-fragments (hi/lo trunc split), kt = 0..1
    short8 Zh[2], Zl[2];
#pragma unroll
    for (int kt = 0; kt < 2; ++kt) {
        float4 v0 = *(const float4*)&z_s[i0 * 64 + kt * 32 + q * 8];
        float4 v1 = *(const float4*)&z_s[i0 * 64 + kt * 32 + q * 8 + 4];
        float vv[8] = {v0.x, v0.y, v0.z, v0.w, v1.x, v1.y, v1.z, v1.w};
        short8 h8, l8;
#pragma unroll
        for (int e = 0; e < 8; ++e) {
            unsigned u = __float_as_uint(vv[e]);
            h8[e] = (short)(u >> 16);
            l8[e] = (short)f2bf(vv[e] - __uint_as_float(u & 0xFFFF0000u));
        }
        Zh[kt] = h8; Zl[kt] = l8;
    }

    // xpr = z@Wz + bz (4 gates) via MFMA
    float4 xpr[4];
    {
        f32x4 accG[4];
#pragma unroll
        for (int g = 0; g < 4; ++g) {
            f32x4 a = (f32x4){0.f, 0.f, 0.f, 0.f};
            int cidx = g * 8 + wid;
#pragma unroll
            for (int kt = 0; kt < 2; ++kt) {
                short8 wh = ((const short8*)Wzh)[((cidx << 1) + kt) * 64 + l];
                short8 wl = ((const short8*)Wzl)[((cidx << 1) + kt) * 64 + l];
                a = __builtin_amdgcn_mfma_f32_16x16x32_bf16(Zh[kt], wh, a, 0, 0, 0);
                a = __builtin_amdgcn_mfma_f32_16x16x32_bf16(Zl[kt], wh, a, 0, 0, 0);
                a = __builtin_amdgcn_mfma_f32_16x16x32_bf16(Zh[kt], wl, a, 0, 0, 0);
            }
            accG[g] = a;
        }
        float b0 = bz[j], b1 = bz[128 + j], b2 = bz[256 + j], b3v = bz[384 + j];
#pragma unroll
        for (int r = 0; r < 4; ++r)
            xpr[r] = make_float4(accG[0][r] + b0, accG[1][r] + b1,
                                 accG[2][r] + b2, accG[3][r] + b3v);
    }

    // h0 = z@Wfc2 + bfc2 via MFMA (ctile = wid) -> hS16[1] (direct u16 writes)
    {
        f32x4 a = (f32x4){0.f, 0.f, 0.f, 0.f};
#pragma unroll
        for (int kt = 0; kt < 2; ++kt) {
            short8 wh = ((const short8*)Wf2h)[((wid << 1) + kt) * 64 + l];
            short8 wl = ((const short8*)Wf2l)[((wid << 1) + kt) * 64 + l];
            a = __builtin_amdgcn_mfma_f32_16x16x32_bf16(Zh[kt], wh, a, 0, 0, 0);
            a = __builtin_amdgcn_mfma_f32_16x16x32_bf16(Zl[kt], wh, a, 0, 0, 0);
            a = __builtin_amdgcn_mfma_f32_16x16x32_bf16(Zh[kt], wl, a, 0, 0, 0);
        }
        float bf = bfc2[j];
#pragma unroll
        for (int r = 0; r < 4; ++r)
            hS16[1][wbase + r * HRS] = f2bf(a[r] + bf);
    }
    __syncthreads();   // h0 visible; all z_s reads complete

    // initial A-fragments from hS16[1]
    short8 Ahi[4];
#pragma unroll
    for (int kt = 0; kt < 4; ++kt) {
        int G = ((4 * kt + q) + 2 * (i0 >> 2)) & 15;
        Ahi[kt] = *(const short8*)&hS16[1][i0 * HRS + G * 8];
    }

    float cC[4] = {};

    for (int t = 0; t < Tt; ++t) {
        unsigned short* hh = hS16[t & 1];

        // ---- gates GEMM (16 MFMA) + pointwise (4 cells) ----
        f32x4 acc[4];
#pragma unroll
        for (int g = 0; g < 4; ++g) acc[g] = (f32x4){0.f, 0.f, 0.f, 0.f};
#pragma unroll
        for (int g = 0; g < 4; ++g)
#pragma unroll
            for (int kt = 0; kt < 4; ++kt)
                acc[g] = __builtin_amdgcn_mfma_f32_16x16x32_bf16(Ahi[kt], Bf[g][kt], acc[g], 0, 0, 0);

#pragma unroll
        for (int r = 0; r < 4; ++r) {
            float4 xg = xpr[r];
            float gi = acc[0][r] + xg.x;
            float gf = acc[1][r] + xg.y;
            float gg = acc[2][r] + xg.z;
            float go = acc[3][r] + xg.w;
            float cn = sigf(gf) * cC[r] + sigf(gi) * ftanh(gg);
            float hn = sigf(go) * ftanh(cn);
            cC[r] = cn;
            hh[wbase + r * HRS] = f2bf(hn);   // direct b16 write, 2 lanes/bank
        }
        __syncthreads();   // single barrier per step (double-buffered h)

        // ---- rebuild A-fragments: 4x b128 ----
#pragma unroll
        for (int kt = 0; kt < 4; ++kt) {
            int G = ((4 * kt + q) + 2 * (i0 >> 2)) & 15;
            Ahi[kt] = *(const short8*)&hh[i0 * HRS + G * 8];
        }

        // ---- pw[n][t][:] = (mask*h_t) @ Wc  (rotating wave; Wc L1-hot) ----
        if (wid == (t & 7)) {
            f32x4 p = (f32x4){0.f, 0.f, 0.f, 0.f};
            bool on = (mk != 0.f);
            short8 zz = (short8)(short)0;
#pragma unroll
            for (int kt = 0; kt < 4; ++kt) {
                short8 wh = ((const short8*)Wchi)[kt * 64 + l];
                p = __builtin_amdgcn_mfma_f32_16x16x32_bf16(on ? Ahi[kt] : zz, wh, p, 0, 0, 0);
            }
#pragma unroll
            for (int r = 0; r < 4; ++r) {
                int n = n0 + q * 4 + r;
                if (n < Nn) pw[((size_t)n * Tt + t) * NFf + i0] = f2bf(p[r]);
            }
        }
    }
}

// ================= aggregate + bias -> out =================
// lane-parallel neighbor prefetch; loop = shfl broadcast + independent gathers.

__global__ __launch_bounds__(256) void agg_out_k(
    const unsigned short* __restrict__ pw, const int* __restrict__ cursor,
    const int* __restrict__ colsrc, const float* __restrict__ bc,
    float* __restrict__ out, int Nn)
{
    int lane = threadIdx.x & 63;
    int n = blockIdx.x * 4 + (threadIdx.x >> 6);
    if (n >= Nn) return;
    int deg = cursor[n]; if (deg > MAXD - 1) deg = MAXD - 1;   // keep slot for self
    float dv = rsqrtf((float)(deg + 1));

    int colv = n;
    float wv = 0.f;
    if (lane < deg) {
        colv = colsrc[(size_t)n * MAXD + lane];
        int dc = cursor[colv]; if (dc > MAXD - 1) dc = MAXD - 1;
        wv = rsqrtf((float)(dc + 1));
    } else if (lane == deg) {
        colv = n; wv = dv;                                     // self loop
    }

    const unsigned int* pw32 = (const unsigned int*)pw;
    float a0 = 0.f, a1 = 0.f, a2 = 0.f, a3 = 0.f;
    int cnt = deg + 1;
    for (int e = 0; e < cnt; ++e) {
        int s = __shfl(colv, e, 64);
        float w = dv * __shfl(wv, e, 64);
        unsigned v0 = pw32[(size_t)s * 96 + lane];
        unsigned v1 = (lane < 32) ? pw32[(size_t)s * 96 + 64 + lane] : 0u;
        a0 += __uint_as_float(v0 << 16) * w;
        a1 += __uint_as_float(v0 & 0xFFFF0000u) * w;
        a2 += __uint_as_float(v1 << 16) * w;
        a3 += __uint_as_float(v1 & 0xFFFF0000u) * w;
    }
    int f0 = (2 * lane) & 15;
    float bc0 = bc[f0], bc1 = bc[f0 + 1];
    float* on = out + (size_t)n * 192;
    *(float2*)&on[2 * lane] = make_float2(a0 + bc0, a1 + bc1);
    if (lane < 32)
        *(float2*)&on[128 + 2 * lane] = make_float2(a2 + bc0, a3 + bc1);
}

// ================= launcher =================

extern "C" void kernel_launch(void* const* d_in, const int* in_sizes, int n_in,
                              void* d_out, int out_size, void* d_ws, size_t ws_size,
                              hipStream_t stream)
{
    const float* z     = (const float*)d_in[0];
    const int*   edge  = (const int*)d_in[1];
    const unsigned char* xmask = (const unsigned char*)d_in[2];
    const float* W_fc2 = (const float*)d_in[3];
    const float* b_fc2 = (const float*)d_in[4];
    const float* W_ih  = (const float*)d_in[5];
    const float* W_hh  = (const float*)d_in[6];
    const float* b_ih  = (const float*)d_in[7];
    const float* b_hh  = (const float*)d_in[8];
    const float* W_gcn = (const float*)d_in[9];
    const float* b_gcn = (const float*)d_in[10];
    const float* W_fc3 = (const float*)d_in[11];
    const float* b_fc3 = (const float*)d_in[12];
    float* out = (float*)d_out;

    const int N = in_sizes[0] / Lz;   // 10000
    const int E = in_sizes[1] / 2;    // 160000

    char* w = (char*)d_ws;
    auto alloc = [&](size_t bytes) { char* p = w; w += (bytes + 255) & ~(size_t)255; return p; };
    unsigned short* pw = (unsigned short*)alloc((size_t)N * Tt * NFf * 2);
    float* mask   = (float*)alloc((size_t)N * 4);
    int*   cursor = (int*)alloc((size_t)N * 4);
    int*   colsrc = (int*)alloc((size_t)N * MAXD * 4);
    unsigned short* Bhi  = (unsigned short*)alloc((size_t)FH * Hh * 2);
    unsigned short* Wchi = (unsigned short*)alloc(4096 * 2);
    unsigned short* Wzh  = (unsigned short*)alloc(32768 * 2);
    unsigned short* Wzl  = (unsigned short*)alloc(32768 * 2);
    unsigned short* Wf2h = (unsigned short*)alloc(8192 * 2);
    unsigned short* Wf2l = (unsigned short*)alloc(8192 * 2);
    float* bz     = (float*)alloc(FH * 4);
    float* bc     = (float*)alloc(NFf * 4);

    hipMemsetAsync(cursor, 0, (size_t)N * 4, stream);

    const int nbm = (N + 255) / 256;
    const int nbd = (E + 255) / 256;
    const int nb16 = (N + 15) / 16;
    const int prep_blocks = nbm + nbd + 256 + 17 + 128 + 2 + 32;

    prep_misc_k<<<prep_blocks, 256, 0, stream>>>(
        xmask, edge, W_hh, W_gcn, W_fc3, b_gcn, b_fc3, W_fc2, W_ih, b_fc2, b_ih, b_hh,
        mask, cursor, colsrc, Bhi, Wchi, bc, Wzh, Wzl, Wf2h, Wf2l, bz, N, E);
    lstm_all_k<<<nb16, 512, 0, stream>>>(z, Wzh, Wzl, Wf2h, Wf2l, bz, b_fc2,
                                         Bhi, Wchi, mask, pw, N);
    agg_out_k<<<(N + 3) / 4, 256, 0, stream>>>(pw, cursor, colsrc, bc, out, N);
}

// Round 21
// 90.014 us; speedup vs baseline: 1.3079x; 1.0119x over previous
//
#include <hip/hip_runtime.h>
#include <hip/hip_bf16.h>

#define Hh   128
#define FH   512
#define Lz   64
#define Tt   12
#define NFf  16
#define MAXD 64    // slot-table max in-degree (Poisson(16): P(>64) ~ 1e-20)
#define HRS  144   // h LDS row stride in ushorts (288B = slot shift 2 per row)

typedef __attribute__((ext_vector_type(8))) short short8;   // 8 bf16 = 4 VGPRs
typedef __attribute__((ext_vector_type(4))) float f32x4;

__device__ __forceinline__ unsigned short f2bf(float x) {   // round-to-nearest-even
    unsigned u = __float_as_uint(x);
    return (unsigned short)((u + 0x7FFF + ((u >> 16) & 1)) >> 16);
}
__device__ __forceinline__ float bf2f(unsigned short s) {
    return __uint_as_float(((unsigned)s) << 16);
}

// ================= fused prep =================
// block ranges: [node_mask | csr-direct | pack_whh | pack_wc | pack_wz | bz | pack_wf2]

__global__ __launch_bounds__(256) void prep_misc_k(
    const unsigned char* __restrict__ xm, const int* __restrict__ edge,
    const float* __restrict__ Whh, const float* __restrict__ Wg,
    const float* __restrict__ W3,  const float* __restrict__ bg,
    const float* __restrict__ b3,  const float* __restrict__ Wf2,
    const float* __restrict__ Wih, const float* __restrict__ bf2,
    const float* __restrict__ bih, const float* __restrict__ bhh,
    float* __restrict__ mask, int* __restrict__ cursor, int* __restrict__ colsrc,
    unsigned short* __restrict__ Bhi, unsigned short* __restrict__ Wchi,
    float* __restrict__ bc,
    unsigned short* __restrict__ Wzh, unsigned short* __restrict__ Wzl,
    unsigned short* __restrict__ Wf2h, unsigned short* __restrict__ Wf2l,
    float* __restrict__ bz,
    int Nn, int E)
{
    int tid = threadIdx.x, b = blockIdx.x;
    int nbm = (Nn + 255) >> 8, nbd = (E + 255) >> 8;
    int t1 = nbm, t2 = t1 + nbd, t3 = t2 + 256, t4 = t3 + 17, t5 = t4 + 128, t6 = t5 + 2;

    if (b < t1) {                    // ---- node_mask ----
        int n = b * 256 + tid;
        if (n >= Nn) return;
        const unsigned int* p = (const unsigned int*)(xm + (size_t)n * 192);
        unsigned int o = 0;
#pragma unroll
        for (int i = 0; i < 48; ++i) o |= p[i];
        mask[n] = o ? 1.0f : 0.0f;
    } else if (b < t2) {             // ---- direct slot-table CSR ----
        int e = (b - t1) * 256 + tid;
        if (e >= E) return;
        int s = edge[e];             s = s < 0 ? 0 : (s >= Nn ? Nn - 1 : s);
        int d = edge[(size_t)E + e]; d = d < 0 ? 0 : (d >= Nn ? Nn - 1 : d);
        int pos = atomicAdd(&cursor[d], 1);
        if (pos < MAXD) colsrc[(size_t)d * MAXD + pos] = s;
    } else if (b < t3) {             // ---- pack W_hh -> B-frag, bf16 hi ----
        int gid = (b - t2) * 256 + tid;      // < 65536
        int e  = gid & 7;
        int l  = (gid >> 3) & 63;
        int kt = (gid >> 9) & 3;
        int c  = gid >> 11;
        int k = kt * 32 + (l >> 4) * 8 + e;
        int j = c * 16 + (l & 15);
        Bhi[gid] = f2bf(Whh[j * Hh + k]);
    } else if (b < t4) {             // ---- pack Wc = Wg@W3 (+bc) ----
        int gid = (b - t3) * 256 + tid;
        if (gid < 4096) {
            int e = gid & 7, l = (gid >> 3) & 63, kt = gid >> 9;
            int k = kt * 32 + (l >> 4) * 8 + e, f = l & 15;
            const float* a = Wg + k * Hh;
            float s = 0.f;
#pragma unroll 4
            for (int h = 0; h < Hh; ++h) s += a[h] * W3[h * NFf + f];
            Wchi[gid] = f2bf(s);
        } else if (gid < 4096 + NFf) {
            int f = gid - 4096;
            float s = b3[f];
#pragma unroll 4
            for (int h = 0; h < Hh; ++h) s += bg[h] * W3[h * NFf + f];
            bc[f] = s;
        }
    } else if (b < t5) {             // ---- pack Wz = Wf2@Wih^T directly in B-frag order, hi/lo ----
        int gid = (b - t4) * 256 + tid;      // < 32768
        int e = gid & 7, l = (gid >> 3) & 63;
        int ktc = gid >> 9;                  // c*2+kt, c<32
        int kt = ktc & 1, c = ktc >> 1;
        int k = kt * 32 + (l >> 4) * 8 + e;  // z-dim (0..63)
        int j = c * 16 + (l & 15);           // gate-col (0..511)
        const float* a = Wf2 + k * Hh;
        const float* bb = Wih + j * Hh;
        float s = 0.f;
#pragma unroll 4
        for (int h = 0; h < Hh; ++h) s += a[h] * bb[h];
        unsigned short hi = f2bf(s);
        Wzh[gid] = hi;
        Wzl[gid] = f2bf(s - bf2f(hi));
    } else if (b < t6) {             // ---- bz = bf2@Wih^T + bih + bhh ----
        int j = (b - t5) * 256 + tid;
        if (j >= FH) return;
        const float* bb = Wih + j * Hh;
        float s = bih[j] + bhh[j];
#pragma unroll 4
        for (int k = 0; k < Hh; ++k) s += bf2[k] * bb[k];
        bz[j] = s;
    } else {                         // ---- pack W_fc2 -> B-frag, hi/lo ----
        int gid = (b - t6) * 256 + tid;      // < 8192
        int e = gid & 7, l = (gid >> 3) & 63;
        int ktc = gid >> 9;                  // c*2+kt, c<8
        int kt = ktc & 1, c = ktc >> 1;
        int k = kt * 32 + (l >> 4) * 8 + e;  // z-dim
        int j = c * 16 + (l & 15);           // hidden col (0..127)
        float v = Wf2[k * Hh + j];
        unsigned short hi = f2bf(v);
        Wf2h[gid] = hi;
        Wf2l[gid] = f2bf(v - bf2f(hi));
    }
}

// ================= whole-sequence LSTM (+MFMA input projections) =================
// 16 rows/block, 8 waves x 512 thr; wave w owns m-tile w; hi-only A in recurrence.
// h exchange via direct ds_write_b16, row stride 144 u16, group swizzle
// G=(g+2*(row>>2))&15 (write exactly 2 lanes/bank). ROUND-21: shared-rcp
// pointwise -- sigma(i)*tanh(g) and sigma(o)*tanh(c) factored to share one
// reciprocal each: 5 exp + 3 rcp per cell (was 5+5). No occupancy floor
// (r15 lesson); no setprio/exp2/kt-outer (r18 regression). Rule #20 throughout.

__global__ __launch_bounds__(512) void lstm_all_k(
    const float* __restrict__ z,
    const unsigned short* __restrict__ Wzh, const unsigned short* __restrict__ Wzl,
    const unsigned short* __restrict__ Wf2h, const unsigned short* __restrict__ Wf2l,
    const float* __restrict__ bz, const float* __restrict__ bfc2,
    const unsigned short* __restrict__ Bhi,
    const unsigned short* __restrict__ Wchi,
    const float* __restrict__ mask,
    unsigned short* __restrict__ pw, int Nn)
{
    __shared__ __align__(16) unsigned short hS16[2][16 * HRS];   // 2 x 4608B
    int tid = threadIdx.x, l = tid & 63, wid = tid >> 6;    // wid = m-tile
    int n0 = blockIdx.x * 16;
    int i0 = l & 15, q = l >> 4;
    int j = wid * 16 + i0;                                  // hidden column

    // write address pieces: row = q*4+r, g = 2*wid + (i0>>3), G = (g+2q)&15
    int wG = ((2 * wid + (i0 >> 3) + 2 * q) & 15) * 8 + (i0 & 7);
    int wbase = q * 4 * HRS + wG;                           // + r*HRS per cell

    // W_hh B-fragments resident (16 short8 = 64 VGPRs)
    short8 Bf[4][4];
#pragma unroll
    for (int g = 0; g < 4; ++g) {
        int cidx = g * 8 + wid;
#pragma unroll
        for (int kt = 0; kt < 4; ++kt)
            Bf[g][kt] = ((const short8*)Bhi)[((cidx << 2) + kt) * 64 + l];
    }

    float mk;
    { int n = n0 + i0; mk = (n < Nn) ? mask[n] : 0.f; }

    // ---- phase 0: stage z (aliased onto hS16[0], 4096B <= 4608B) ----
    float* z_s = (float*)&hS16[0][0];
    for (int idx = tid; idx < 16 * Lz; idx += 512) {
        int r = idx >> 6, k = idx & 63;
        int n = n0 + r;
        z_s[idx] = (n < Nn) ? z[(size_t)n * Lz + k] : 0.f;
    }
    __syncthreads();

    // z A-fragments (hi/lo trunc split), kt = 0..1
    short8 Zh[2], Zl[2];
#pragma unroll
    for (int kt = 0; kt < 2; ++kt) {
        float4 v0 = *(const float4*)&z_s[i0 * 64 + kt * 32 + q * 8];
        float4 v1 = *(const float4*)&z_s[i0 * 64 + kt * 32 + q * 8 + 4];
        float vv[8] = {v0.x, v0.y, v0.z, v0.w, v1.x, v1.y, v1.z, v1.w};
        short8 h8, l8;
#pragma unroll
        for (int e = 0; e < 8; ++e) {
            unsigned u = __float_as_uint(vv[e]);
            h8[e] = (short)(u >> 16);
            l8[e] = (short)f2bf(vv[e] - __uint_as_float(u & 0xFFFF0000u));
        }
        Zh[kt] = h8; Zl[kt] = l8;
    }

    // xpr = z@Wz + bz (4 gates) via MFMA
    float4 xpr[4];
    {
        f32x4 accG[4];
#pragma unroll
        for (int g = 0; g < 4; ++g) {
            f32x4 a = (f32x4){0.f, 0.f, 0.f, 0.f};
            int cidx = g * 8 + wid;
#pragma unroll
            for (int kt = 0; kt < 2; ++kt) {
                short8 wh = ((const short8*)Wzh)[((cidx << 1) + kt) * 64 + l];
                short8 wl = ((const short8*)Wzl)[((cidx << 1) + kt) * 64 + l];
                a = __builtin_amdgcn_mfma_f32_16x16x32_bf16(Zh[kt], wh, a, 0, 0, 0);
                a = __builtin_amdgcn_mfma_f32_16x16x32_bf16(Zl[kt], wh, a, 0, 0, 0);
                a = __builtin_amdgcn_mfma_f32_16x16x32_bf16(Zh[kt], wl, a, 0, 0, 0);
            }
            accG[g] = a;
        }
        float b0 = bz[j], b1 = bz[128 + j], b2 = bz[256 + j], b3v = bz[384 + j];
#pragma unroll
        for (int r = 0; r < 4; ++r)
            xpr[r] = make_float4(accG[0][r] + b0, accG[1][r] + b1,
                                 accG[2][r] + b2, accG[3][r] + b3v);
    }

    // h0 = z@Wfc2 + bfc2 via MFMA (ctile = wid) -> hS16[1] (direct u16 writes)
    {
        f32x4 a = (f32x4){0.f, 0.f, 0.f, 0.f};
#pragma unroll
        for (int kt = 0; kt < 2; ++kt) {
            short8 wh = ((const short8*)Wf2h)[((wid << 1) + kt) * 64 + l];
            short8 wl = ((const short8*)Wf2l)[((wid << 1) + kt) * 64 + l];
            a = __builtin_amdgcn_mfma_f32_16x16x32_bf16(Zh[kt], wh, a, 0, 0, 0);
            a = __builtin_amdgcn_mfma_f32_16x16x32_bf16(Zl[kt], wh, a, 0, 0, 0);
            a = __builtin_amdgcn_mfma_f32_16x16x32_bf16(Zh[kt], wl, a, 0, 0, 0);
        }
        float bf = bfc2[j];
#pragma unroll
        for (int r = 0; r < 4; ++r)
            hS16[1][wbase + r * HRS] = f2bf(a[r] + bf);
    }
    __syncthreads();   // h0 visible; all z_s reads complete

    // initial A-fragments from hS16[1]
    short8 Ahi[4];
#pragma unroll
    for (int kt = 0; kt < 4; ++kt) {
        int G = ((4 * kt + q) + 2 * (i0 >> 2)) & 15;
        Ahi[kt] = *(const short8*)&hS16[1][i0 * HRS + G * 8];
    }

    float cC[4] = {};

    for (int t = 0; t < Tt; ++t) {
        unsigned short* hh = hS16[t & 1];

        // ---- gates GEMM (16 MFMA) + pointwise (4 cells) ----
        f32x4 acc[4];
#pragma unroll
        for (int g = 0; g < 4; ++g) acc[g] = (f32x4){0.f, 0.f, 0.f, 0.f};
#pragma unroll
        for (int g = 0; g < 4; ++g)
#pragma unroll
            for (int kt = 0; kt < 4; ++kt)
                acc[g] = __builtin_amdgcn_mfma_f32_16x16x32_bf16(Ahi[kt], Bf[g][kt], acc[g], 0, 0, 0);

#pragma unroll
        for (int r = 0; r < 4; ++r) {
            float4 xg = xpr[r];
            float gi = acc[0][r] + xg.x;
            float gf = acc[1][r] + xg.y;
            float gg = acc[2][r] + xg.z;
            float go = acc[3][r] + xg.w;
            // shared-rcp pointwise: 5 exp + 3 rcp
            float ei = __expf(-gi);
            float ef = __expf(-gf);
            float eo = __expf(-go);
            float gc = fminf(fmaxf(gg, -15.f), 15.f);
            float eg = __expf(-2.f * gc);
            float cn = cC[r] * __builtin_amdgcn_rcpf(1.f + ef)
                     + (1.f - eg) * __builtin_amdgcn_rcpf((1.f + ei) * (1.f + eg));
            float cl = fminf(fmaxf(cn, -15.f), 15.f);
            float ec = __expf(-2.f * cl);
            float hn = (1.f - ec) * __builtin_amdgcn_rcpf((1.f + eo) * (1.f + ec));
            cC[r] = cn;
            hh[wbase + r * HRS] = f2bf(hn);   // direct b16 write, 2 lanes/bank
        }
        __syncthreads();   // single barrier per step (double-buffered h)

        // ---- rebuild A-fragments: 4x b128 ----
#pragma unroll
        for (int kt = 0; kt < 4; ++kt) {
            int G = ((4 * kt + q) + 2 * (i0 >> 2)) & 15;
            Ahi[kt] = *(const short8*)&hh[i0 * HRS + G * 8];
        }

        // ---- pw[n][t][:] = (mask*h_t) @ Wc  (rotating wave; Wc L1-hot) ----
        if (wid == (t & 7)) {
            f32x4 p = (f32x4){0.f, 0.f, 0.f, 0.f};
            bool on = (mk != 0.f);
            short8 zz = (short8)(short)0;
#pragma unroll
            for (int kt = 0; kt < 4; ++kt) {
                short8 wh = ((const short8*)Wchi)[kt * 64 + l];
                p = __builtin_amdgcn_mfma_f32_16x16x32_bf16(on ? Ahi[kt] : zz, wh, p, 0, 0, 0);
            }
#pragma unroll
            for (int r = 0; r < 4; ++r) {
                int n = n0 + q * 4 + r;
                if (n < Nn) pw[((size_t)n * Tt + t) * NFf + i0] = f2bf(p[r]);
            }
        }
    }
}

// ================= aggregate + bias -> out =================
// lane-parallel neighbor prefetch (weights pre-multiplied by dv);
// loop = shfl broadcast + independent gathers.

__global__ __launch_bounds__(256) void agg_out_k(
    const unsigned short* __restrict__ pw, const int* __restrict__ cursor,
    const int* __restrict__ colsrc, const float* __restrict__ bc,
    float* __restrict__ out, int Nn)
{
    int lane = threadIdx.x & 63;
    int n = blockIdx.x * 4 + (threadIdx.x >> 6);
    if (n >= Nn) return;
    int deg = cursor[n]; if (deg > MAXD - 1) deg = MAXD - 1;   // keep slot for self
    float dv = rsqrtf((float)(deg + 1));

    int colv = n;
    float wv = 0.f;
    if (lane < deg) {
        colv = colsrc[(size_t)n * MAXD + lane];
        int dc = cursor[colv]; if (dc > MAXD - 1) dc = MAXD - 1;
        wv = dv * rsqrtf((float)(dc + 1));                     // dv pre-folded
    } else if (lane == deg) {
        colv = n; wv = dv * dv;                                // self loop
    }

    const unsigned int* pw32 = (const unsigned int*)pw;
    float a0 = 0.f, a1 = 0.f, a2 = 0.f, a3 = 0.f;
    int cnt = deg + 1;
    for (int e = 0; e < cnt; ++e) {
        int s = __shfl(colv, e, 64);
        float w = __shfl(wv, e, 64);
        unsigned v0 = pw32[(size_t)s * 96 + lane];
        unsigned v1 = (lane < 32) ? pw32[(size_t)s * 96 + 64 + lane] : 0u;
        a0 += __uint_as_float(v0 << 16) * w;
        a1 += __uint_as_float(v0 & 0xFFFF0000u) * w;
        a2 += __uint_as_float(v1 << 16) * w;
        a3 += __uint_as_float(v1 & 0xFFFF0000u) * w;
    }
    int f0 = (2 * lane) & 15;
    float bc0 = bc[f0], bc1 = bc[f0 + 1];
    float* on = out + (size_t)n * 192;
    *(float2*)&on[2 * lane] = make_float2(a0 + bc0, a1 + bc1);
    if (lane < 32)
        *(float2*)&on[128 + 2 * lane] = make_float2(a2 + bc0, a3 + bc1);
}

// ================= launcher =================

extern "C" void kernel_launch(void* const* d_in, const int* in_sizes, int n_in,
                              void* d_out, int out_size, void* d_ws, size_t ws_size,
                              hipStream_t stream)
{
    const float* z     = (const float*)d_in[0];
    const int*   edge  = (const int*)d_in[1];
    const unsigned char* xmask = (const unsigned char*)d_in[2];
    const float* W_fc2 = (const float*)d_in[3];
    const float* b_fc2 = (const float*)d_in[4];
    const float* W_ih  = (const float*)d_in[5];
    const float* W_hh  = (const float*)d_in[6];
    const float* b_ih  = (const float*)d_in[7];
    const float* b_hh  = (const float*)d_in[8];
    const float* W_gcn = (const float*)d_in[9];
    const float* b_gcn = (const float*)d_in[10];
    const float* W_fc3 = (const float*)d_in[11];
    const float* b_fc3 = (const float*)d_in[12];
    float* out = (float*)d_out;

    const int N = in_sizes[0] / Lz;   // 10000
    const int E = in_sizes[1] / 2;    // 160000

    char* w = (char*)d_ws;
    auto alloc = [&](size_t bytes) { char* p = w; w += (bytes + 255) & ~(size_t)255; return p; };
    unsigned short* pw = (unsigned short*)alloc((size_t)N * Tt * NFf * 2);
    float* mask   = (float*)alloc((size_t)N * 4);
    int*   cursor = (int*)alloc((size_t)N * 4);
    int*   colsrc = (int*)alloc((size_t)N * MAXD * 4);
    unsigned short* Bhi  = (unsigned short*)alloc((size_t)FH * Hh * 2);
    unsigned short* Wchi = (unsigned short*)alloc(4096 * 2);
    unsigned short* Wzh  = (unsigned short*)alloc(32768 * 2);
    unsigned short* Wzl  = (unsigned short*)alloc(32768 * 2);
    unsigned short* Wf2h = (unsigned short*)alloc(8192 * 2);
    unsigned short* Wf2l = (unsigned short*)alloc(8192 * 2);
    float* bz     = (float*)alloc(FH * 4);
    float* bc     = (float*)alloc(NFf * 4);

    hipMemsetAsync(cursor, 0, (size_t)N * 4, stream);

    const int nbm = (N + 255) / 256;
    const int nbd = (E + 255) / 256;
    const int nb16 = (N + 15) / 16;
    const int prep_blocks = nbm + nbd + 256 + 17 + 128 + 2 + 32;

    prep_misc_k<<<prep_blocks, 256, 0, stream>>>(
        xmask, edge, W_hh, W_gcn, W_fc3, b_gcn, b_fc3, W_fc2, W_ih, b_fc2, b_ih, b_hh,
        mask, cursor, colsrc, Bhi, Wchi, bc, Wzh, Wzl, Wf2h, Wf2l, bz, N, E);
    lstm_all_k<<<nb16, 512, 0, stream>>>(z, Wzh, Wzl, Wf2h, Wf2l, bz, b_fc2,
                                         Bhi, Wchi, mask, pw, N);
    agg_out_k<<<(N + 3) / 4, 256, 0, stream>>>(pw, cursor, colsrc, bc, out, N);
}